// Round 4
// baseline (298.910 us; speedup 1.0000x reference)
//
#include <hip/hip_runtime.h>
#include <math.h>

#define IMG_W 512
#define IMG_H 512
#define NPLANES 48      // 16 * 3
#define RROWS 32        // output rows per wave-tile (512 = 32*16 exact)
#define NCHUNK 16
#define NSTRIP 8        // 512 / 64 cols
#define NSUB (NPLANES * NSTRIP * NCHUNK)   // 6144 wave-tiles
#define WPB 4                              // waves per workgroup
#define NBLOCKS (NSUB / WPB)               // 1536
#define SSIM_C1 1e-4f
#define SSIM_C2 9e-4f

struct GW { float g[11]; };

__device__ __forceinline__ float fdiv_fast(float n, float d) {
  float r = __builtin_amdgcn_rcpf(d);
  r = r * fmaf(-d, r, 2.0f);      // 1 Newton step on reciprocal
  float q = n * r;
  q = fmaf(fmaf(-d, q, n), r, q); // residual correction
  return q;
}

// 4 independent waves per workgroup; each wave owns a 64-col x 32-row output
// tile and a PRIVATE LDS slice (no barriers anywhere: single-wave data flow,
// in-order DS pipe, double-buffered row).
// 7 ring streams: A, B, F, (A^2+F^2), (B^2+F^2), AF, BF -- the variance sums
// are merged at ring-write time (conv is linear), saving 11 VGPRs and 11
// vconv FMAs/row. __launch_bounds__(256,3): VGPR cap ~170 >> ~115 live, so
// the ring stays in arch VGPRs (round 2's cap of 100 caused AGPR churn).
__global__ __launch_bounds__(256, 3) void ssim_main(
    const float* __restrict__ A, const float* __restrict__ B,
    const float* __restrict__ F, double* __restrict__ partials, GW gw)
{
  __shared__ float sA[WPB][2][80], sB[WPB][2][80], sF[WPB][2][80];
  const int t = threadIdx.x & 63;            // lane within wave
  const int w = threadIdx.x >> 6;            // wave within block
  const int sb = blockIdx.x * WPB + w;       // wave-tile id, 0..6143
  const int plane = sb / (NSTRIP * NCHUNK);
  const int rem   = sb % (NSTRIP * NCHUNK);
  const int strip = rem / NCHUNK;
  const int chunk = rem % NCHUNK;
  const int x0 = strip * 64;
  const int y0 = chunk * RROWS;
  const size_t pbase = (size_t)plane * (IMG_W * IMG_H);
  const float* Ap = A + pbase;
  const float* Bp = B + pbase;
  const float* Fp = F + pbase;

  const int c  = x0 - 5 + t;                 // primary load column
  const bool cok = (c >= 0) && (c < IMG_W);
  const int c2 = c + 64;                     // halo column (lanes 0..9)
  const bool c2ok = (t < 10) && (c2 < IMG_W);

  // ring[stream][slot]: horizontally-convolved rows, slot = input-row mod 11
  float ring[7][11];
  #pragma unroll
  for (int s = 0; s < 7; ++s)
    #pragma unroll
    for (int k = 0; k < 11; ++k) ring[s][k] = 0.f;

  float acc = 0.f;

  // prefetch registers for the software pipeline
  float rA, rB, rF, xA, xB, xF;
  auto load_row = [&](int ii) {
    const int yin = y0 - 5 + ii;
    const bool rok = (yin >= 0) && (yin < IMG_H);
    const size_t roff = (size_t)yin * IMG_W;
    rA = (rok && cok) ? Ap[roff + c] : 0.f;
    rB = (rok && cok) ? Bp[roff + c] : 0.f;
    rF = (rok && cok) ? Fp[roff + c] : 0.f;
    xA = (rok && c2ok) ? Ap[roff + c2] : 0.f;
    xB = (rok && c2ok) ? Bp[roff + c2] : 0.f;
    xF = (rok && c2ok) ? Fp[roff + c2] : 0.f;
  };

  load_row(0);   // preload row 0

  #pragma unroll 1
  for (int jj = 0; jj < 4; ++jj) {
    #pragma unroll
    for (int ph = 0; ph < 11; ++ph) {
      const int ii = jj * 11 + ph;           // input-row counter; ii % 11 == ph
      if (ii <= RROWS + 9) {                 // 0..41
        const int buf = ii & 1;
        // --- stage prefetched row into this wave's LDS slice ---
        sA[w][buf][t] = rA; sB[w][buf][t] = rB; sF[w][buf][t] = rF;
        if (t < 10) {
          sA[w][buf][t+64] = xA; sB[w][buf][t+64] = xB; sF[w][buf][t+64] = xF;
        }
        // --- issue NEXT row's global loads; latency hidden under the convs ---
        if (ii < RROWS + 9) load_row(ii + 1);
        // --- horizontal 11-tap conv of the 8 product streams ---
        float hA=0,hB=0,hF=0,hA2=0,hB2=0,hF2=0,hAF=0,hBF=0;
        #pragma unroll
        for (int k = 0; k < 11; ++k) {
          const float wt = gw.g[k];
          const float a = sA[w][buf][t+k], bb = sB[w][buf][t+k], f = sF[w][buf][t+k];
          const float wa = wt*a, wb = wt*bb, wf = wt*f;
          hA += wa; hB += wb; hF += wf;
          hA2 = fmaf(wa, a, hA2); hB2 = fmaf(wb, bb, hB2); hF2 = fmaf(wf, f, hF2);
          hAF = fmaf(wa, f, hAF); hBF = fmaf(wb, f, hBF);
        }
        // merge variance streams at ring-write (conv linearity): 7 rings
        ring[0][ph]=hA;  ring[1][ph]=hB;  ring[2][ph]=hF;
        ring[3][ph]=hA2+hF2;  ring[4][ph]=hB2+hF2;
        ring[5][ph]=hAF; ring[6][ph]=hBF;

        // --- vertical 11-tap conv + SSIM map once 11 rows are live ---
        if (ii >= 10) {                      // yout = y0+ii-10, always in range
          float m[7];
          #pragma unroll
          for (int s = 0; s < 7; ++s) m[s] = 0.f;
          #pragma unroll
          for (int k = 0; k < 11; ++k) {
            const int sl = (ph + 1 + k) % 11;   // compile-time constant
            const float wt = gw.g[k];
            #pragma unroll
            for (int s = 0; s < 7; ++s) m[s] = fmaf(wt, ring[s][sl], m[s]);
          }
          const float mA=m[0], mB=m[1], mF=m[2];
          const float vS1=m[3], vS2=m[4], vAF=m[5], vBF=m[6];
          const float mA2=mA*mA, mB2=mB*mB, mF2=mF*mF, mAF=mA*mF, mBF=mB*mF;
          const float sAF = vAF - mAF, sBF = vBF - mBF;
          const float ts1 = vS1 - mA2 - mF2;   // sigmaA^2 + sigmaF^2
          const float ts2 = vS2 - mB2 - mF2;   // sigmaB^2 + sigmaF^2
          const float n1 = fmaf(2.f, mAF, SSIM_C1) * fmaf(2.f, sAF, SSIM_C2);
          const float d1 = (mA2 + mF2 + SSIM_C1) * (ts1 + SSIM_C2);
          const float n2 = fmaf(2.f, mBF, SSIM_C1) * fmaf(2.f, sBF, SSIM_C2);
          const float d2 = (mB2 + mF2 + SSIM_C1) * (ts2 + SSIM_C2);
          acc += fdiv_fast(n1, d1) + fdiv_fast(n2, d2);
        }
      }
    }
  }

  // wave (64-lane) reduction, one plain store per wave-tile
  float wsum = acc;
  #pragma unroll
  for (int off = 32; off > 0; off >>= 1)
    wsum += __shfl_down(wsum, off, 64);
  if (t == 0) partials[sb] = (double)wsum;
}

__global__ __launch_bounds__(256) void ssim_final(
    const double* __restrict__ partials, float* __restrict__ out)
{
  __shared__ double sd[256];
  const int t = threadIdx.x;
  double s = 0.0;
  for (int i = t; i < NSUB; i += 256) s += partials[i];
  sd[t] = s;
  __syncthreads();
  for (int off = 128; off > 0; off >>= 1) {
    if (t < off) sd[t] += sd[t + off];
    __syncthreads();
  }
  if (t == 0)
    out[0] = (float)(0.5 * sd[0] / (double)(16.0 * 3.0 * 512.0 * 512.0));
}

extern "C" void kernel_launch(void* const* d_in, const int* in_sizes, int n_in,
                              void* d_out, int out_size, void* d_ws, size_t ws_size,
                              hipStream_t stream) {
  const float* A = (const float*)d_in[0];
  const float* B = (const float*)d_in[1];
  const float* F = (const float*)d_in[2];
  double* partials = (double*)d_ws;   // NSUB doubles = 48 KB

  GW gw;
  double g[11], s = 0.0;
  for (int i = 0; i < 11; ++i) { g[i] = exp(-((double)((i-5)*(i-5))) / 4.5); s += g[i]; }
  for (int i = 0; i < 11; ++i) gw.g[i] = (float)(g[i] / s);

  hipLaunchKernelGGL(ssim_main, dim3(NBLOCKS), dim3(256), 0, stream,
                     A, B, F, partials, gw);
  hipLaunchKernelGGL(ssim_final, dim3(1), dim3(256), 0, stream,
                     partials, (float*)d_out);
}

// Round 5
// 245.086 us; speedup vs baseline: 1.2196x; 1.2196x over previous
//
#include <hip/hip_runtime.h>
#include <math.h>

#define IMG_W 512
#define IMG_H 512
#define NPLANES 48      // 16 * 3
#define RROWS 32        // output rows per block (512 = 32*16 exact)
#define NCHUNK 16
#define NSTRIP 8        // 512 / 64 cols
#define NBLOCKS (NPLANES * NSTRIP * NCHUNK)   // 6144
#define SSIM_C1 1e-4f
#define SSIM_C2 9e-4f

struct GW { float g[11]; };

__device__ __forceinline__ float fdiv_fast(float n, float d) {
  float r = __builtin_amdgcn_rcpf(d);
  r = r * fmaf(-d, r, 2.0f);      // 1 Newton step on reciprocal
  float q = n * r;
  q = fmaf(fmaf(-d, q, n), r, q); // residual correction
  return q;
}

// One wave per block; 64 output columns x 32 output rows per block.
// No __syncthreads: single-wave block + double-buffered LDS row; in-wave LDS
// write->read ordering is enforced by compiler lgkmcnt waits.
// __launch_bounds__(64, 2): floor of 2 waves/EU -> VGPR cap 256. Round 2's
// compiler-default cap of 100 forced the 77-reg ring through AGPR shuttles
// (~2x VALU instr inflation); round 4's (256,3) caused actual scratch spills
// (WRITE_SIZE 15 MB). This keeps all ~130 live values in arch VGPRs.
// 7 ring streams: A, B, F, (A^2+F^2), (B^2+F^2), AF, BF -- variance sums
// merged at ring-write time (conv linearity; verified exact in round 4).
__global__ __launch_bounds__(64, 2) void ssim_main(
    const float* __restrict__ A, const float* __restrict__ B,
    const float* __restrict__ F, double* __restrict__ partials, GW gw)
{
  __shared__ float sA[2][80], sB[2][80], sF[2][80];
  const int b = blockIdx.x;
  const int plane = b / (NSTRIP * NCHUNK);
  const int rem   = b % (NSTRIP * NCHUNK);
  const int strip = rem / NCHUNK;
  const int chunk = rem % NCHUNK;
  const int x0 = strip * 64;
  const int y0 = chunk * RROWS;
  const int t = threadIdx.x;
  const size_t pbase = (size_t)plane * (IMG_W * IMG_H);
  const float* Ap = A + pbase;
  const float* Bp = B + pbase;
  const float* Fp = F + pbase;

  const int c  = x0 - 5 + t;                 // primary load column
  const bool cok = (c >= 0) && (c < IMG_W);
  const int c2 = c + 64;                     // halo column (lanes 0..9)
  const bool c2ok = (t < 10) && (c2 < IMG_W);

  // ring[stream][slot]: horizontally-convolved rows, slot = input-row mod 11
  float ring[7][11];
  #pragma unroll
  for (int s = 0; s < 7; ++s)
    #pragma unroll
    for (int k = 0; k < 11; ++k) ring[s][k] = 0.f;

  float acc = 0.f;

  // prefetch registers for the software pipeline
  float rA, rB, rF, xA, xB, xF;
  auto load_row = [&](int ii) {
    const int yin = y0 - 5 + ii;
    const bool rok = (yin >= 0) && (yin < IMG_H);
    const size_t roff = (size_t)yin * IMG_W;
    rA = (rok && cok) ? Ap[roff + c] : 0.f;
    rB = (rok && cok) ? Bp[roff + c] : 0.f;
    rF = (rok && cok) ? Fp[roff + c] : 0.f;
    xA = (rok && c2ok) ? Ap[roff + c2] : 0.f;
    xB = (rok && c2ok) ? Bp[roff + c2] : 0.f;
    xF = (rok && c2ok) ? Fp[roff + c2] : 0.f;
  };

  load_row(0);   // preload row 0

  for (int jj = 0; jj < 4; ++jj) {
    #pragma unroll
    for (int ph = 0; ph < 11; ++ph) {
      const int ii = jj * 11 + ph;           // input-row counter; ii % 11 == ph
      if (ii <= RROWS + 9) {                 // 0..41
        const int buf = ii & 1;
        // --- stage prefetched row into LDS (double-buffered, no barrier) ---
        sA[buf][t] = rA; sB[buf][t] = rB; sF[buf][t] = rF;
        if (t < 10) { sA[buf][t+64] = xA; sB[buf][t+64] = xB; sF[buf][t+64] = xF; }
        // --- issue NEXT row's global loads; latency hidden under the convs ---
        if (ii < RROWS + 9) load_row(ii + 1);
        // --- horizontal 11-tap conv of the 8 product streams ---
        float hA=0,hB=0,hF=0,hA2=0,hB2=0,hF2=0,hAF=0,hBF=0;
        #pragma unroll
        for (int k = 0; k < 11; ++k) {
          const float w = gw.g[k];
          const float a = sA[buf][t+k], bb = sB[buf][t+k], f = sF[buf][t+k];
          const float wa = w*a, wb = w*bb, wf = w*f;
          hA += wa; hB += wb; hF += wf;
          hA2 = fmaf(wa, a, hA2); hB2 = fmaf(wb, bb, hB2); hF2 = fmaf(wf, f, hF2);
          hAF = fmaf(wa, f, hAF); hBF = fmaf(wb, f, hBF);
        }
        // merge variance streams at ring-write (conv linearity): 7 rings
        ring[0][ph]=hA;  ring[1][ph]=hB;  ring[2][ph]=hF;
        ring[3][ph]=hA2+hF2;  ring[4][ph]=hB2+hF2;
        ring[5][ph]=hAF; ring[6][ph]=hBF;

        // --- vertical 11-tap conv + SSIM map once 11 rows are live ---
        if (ii >= 10) {                      // yout = y0+ii-10, always in range
          float m[7];
          #pragma unroll
          for (int s = 0; s < 7; ++s) m[s] = 0.f;
          #pragma unroll
          for (int k = 0; k < 11; ++k) {
            const int sl = (ph + 1 + k) % 11;   // compile-time constant
            const float w = gw.g[k];
            #pragma unroll
            for (int s = 0; s < 7; ++s) m[s] = fmaf(w, ring[s][sl], m[s]);
          }
          const float mA=m[0], mB=m[1], mF=m[2];
          const float vS1=m[3], vS2=m[4], vAF=m[5], vBF=m[6];
          const float mA2=mA*mA, mB2=mB*mB, mF2=mF*mF, mAF=mA*mF, mBF=mB*mF;
          const float sAF = vAF - mAF, sBF = vBF - mBF;
          const float ts1 = vS1 - mA2 - mF2;   // sigmaA^2 + sigmaF^2
          const float ts2 = vS2 - mB2 - mF2;   // sigmaB^2 + sigmaF^2
          const float n1 = fmaf(2.f, mAF, SSIM_C1) * fmaf(2.f, sAF, SSIM_C2);
          const float d1 = (mA2 + mF2 + SSIM_C1) * (ts1 + SSIM_C2);
          const float n2 = fmaf(2.f, mBF, SSIM_C1) * fmaf(2.f, sBF, SSIM_C2);
          const float d2 = (mB2 + mF2 + SSIM_C1) * (ts2 + SSIM_C2);
          acc += fdiv_fast(n1, d1) + fdiv_fast(n2, d2);
        }
      }
    }
  }

  // wave (64-lane) reduction, one plain store per block (no atomics, no init)
  float wsum = acc;
  #pragma unroll
  for (int off = 32; off > 0; off >>= 1)
    wsum += __shfl_down(wsum, off, 64);
  if (t == 0) partials[b] = (double)wsum;
}

__global__ __launch_bounds__(256) void ssim_final(
    const double* __restrict__ partials, float* __restrict__ out)
{
  __shared__ double sd[256];
  const int t = threadIdx.x;
  double s = 0.0;
  for (int i = t; i < NBLOCKS; i += 256) s += partials[i];
  sd[t] = s;
  __syncthreads();
  for (int off = 128; off > 0; off >>= 1) {
    if (t < off) sd[t] += sd[t + off];
    __syncthreads();
  }
  if (t == 0)
    out[0] = (float)(0.5 * sd[0] / (double)(16.0 * 3.0 * 512.0 * 512.0));
}

extern "C" void kernel_launch(void* const* d_in, const int* in_sizes, int n_in,
                              void* d_out, int out_size, void* d_ws, size_t ws_size,
                              hipStream_t stream) {
  const float* A = (const float*)d_in[0];
  const float* B = (const float*)d_in[1];
  const float* F = (const float*)d_in[2];
  double* partials = (double*)d_ws;   // NBLOCKS doubles = 48 KB

  GW gw;
  double g[11], s = 0.0;
  for (int i = 0; i < 11; ++i) { g[i] = exp(-((double)((i-5)*(i-5))) / 4.5); s += g[i]; }
  for (int i = 0; i < 11; ++i) gw.g[i] = (float)(g[i] / s);

  hipLaunchKernelGGL(ssim_main, dim3(NBLOCKS), dim3(64), 0, stream,
                     A, B, F, partials, gw);
  hipLaunchKernelGGL(ssim_final, dim3(1), dim3(256), 0, stream,
                     partials, (float*)d_out);
}